// Round 1
// baseline (3571.960 us; speedup 1.0000x reference)
//
#include <hip/hip_runtime.h>
#include <math.h>

#define CC 21
#define HH 512
#define WW 512
#define HWN (HH*WW)
#define CHW (CC*HWN)
#define RAD 7
#define KS 15
#define NITER 5

// ---------------------------------------------------------------------------
// init: M1 = CM@SKW, M2 = CM@BKW  (21x21 each), gaussian taps (sigma 3, 10)
// ---------------------------------------------------------------------------
__global__ void k_init_small(const float* __restrict__ cm,
                             const float* __restrict__ skw,
                             const float* __restrict__ bkw,
                             float* __restrict__ M1, float* __restrict__ M2,
                             float* __restrict__ kbuf) {
    int t = threadIdx.x;
    if (t < CC*CC) {
        int i = t / CC, j = t % CC;
        float a = 0.f, b = 0.f;
        for (int k = 0; k < CC; ++k) {
            a += cm[i*CC+k] * skw[k*CC+j];
            b += cm[i*CC+k] * bkw[k*CC+j];
        }
        M1[t] = a; M2[t] = b;
    }
    if (t == CC*CC) {
        float w3[KS], w10[KS];
        float s3 = 0.f, s10 = 0.f;
        for (int i = 0; i < KS; ++i) {
            float x = (float)(i - RAD);
            w3[i]  = expf(-0.5f * (x/3.0f)  * (x/3.0f));
            w10[i] = expf(-0.5f * (x/10.0f) * (x/10.0f));
            s3 += w3[i]; s10 += w10[i];
        }
        for (int i = 0; i < KS; ++i) {
            kbuf[i]      = w3[i]  / s3;
            kbuf[KS + i] = w10[i] / s10;
        }
    }
}

// guide(h,w), spmT(h,w) = sp_map[w][h], q(c,h,w) = unaries[h][w][c]
__global__ void k_init_maps(const float* __restrict__ rgb,
                            const int* __restrict__ spin,
                            const float* __restrict__ un,
                            float* __restrict__ guide,
                            int* __restrict__ spmT,
                            float* __restrict__ q) {
    int p = blockIdx.x * blockDim.x + threadIdx.x;
    if (p >= HWN) return;
    int h = p / WW, w = p - h*WW;
    float r = rgb[p*3+0] * (1.0f/255.0f);
    float g = rgb[p*3+1] * (1.0f/255.0f);
    float b = rgb[p*3+2] * (1.0f/255.0f);
    guide[p] = expf(-0.5f * (r*r + g*g + b*b) / 9.0f);   // theta_beta^2 = 9
    spmT[p] = spin[w*HH + h];
    #pragma unroll
    for (int c = 0; c < CC; ++c) q[c*HWN + p] = un[p*CC + c];
}

// ---------------------------------------------------------------------------
// vertical blur (fused spatial sigma=3 + bilateral sigma=10 with guide premul)
// in == nullptr means input === 1.0  (norm computation)
// ---------------------------------------------------------------------------
__global__ void k_vblur(const float* __restrict__ in,
                        const float* __restrict__ guide,
                        float* __restrict__ outs, float* __restrict__ outb,
                        const float* __restrict__ kbuf, int nc) {
    __shared__ float k3[KS], k10[KS];
    if (threadIdx.x < KS) {
        k3[threadIdx.x]  = kbuf[threadIdx.x];
        k10[threadIdx.x] = kbuf[KS + threadIdx.x];
    }
    __syncthreads();
    int idx = blockIdx.x * blockDim.x + threadIdx.x;
    if (idx >= nc * HWN) return;
    int c = idx / HWN, p = idx - c*HWN;
    int h = p / WW, w = p - h*WW;
    float as = 0.f, ab = 0.f;
    #pragma unroll
    for (int d = 0; d < KS; ++d) {
        int hh = h + d - RAD;
        if (hh >= 0 && hh < HH) {
            int pp = hh*WW + w;
            float v = in ? in[c*HWN + pp] : 1.0f;
            as += k3[d] * v;
            ab += k10[d] * (v * guide[pp]);
        }
    }
    outs[idx] = as;
    outb[idx] = ab;
}

// horizontal blur; optional division by norms (null -> no division)
__global__ void k_hblur(const float* __restrict__ ins,
                        const float* __restrict__ inb,
                        float* __restrict__ outs, float* __restrict__ outb,
                        const float* __restrict__ snorm,
                        const float* __restrict__ bnorm,
                        const float* __restrict__ kbuf, int nc) {
    __shared__ float k3[KS], k10[KS];
    if (threadIdx.x < KS) {
        k3[threadIdx.x]  = kbuf[threadIdx.x];
        k10[threadIdx.x] = kbuf[KS + threadIdx.x];
    }
    __syncthreads();
    int idx = blockIdx.x * blockDim.x + threadIdx.x;
    if (idx >= nc * HWN) return;
    int c = idx / HWN, p = idx - c*HWN;
    int h = p / WW, w = p - h*WW;
    float as = 0.f, ab = 0.f;
    int rowbase = c*HWN + h*WW;
    #pragma unroll
    for (int d = 0; d < KS; ++d) {
        int ww = w + d - RAD;
        if (ww >= 0 && ww < WW) {
            as += k3[d]  * ins[rowbase + ww];
            ab += k10[d] * inb[rowbase + ww];
        }
    }
    if (snorm) { as /= snorm[p]; ab /= bnorm[p]; }
    outs[idx] = as;
    outb[idx] = ab;
}

// ---------------------------------------------------------------------------
// channel softmax per pixel
// ---------------------------------------------------------------------------
__global__ void k_softmax(const float* __restrict__ q, float* __restrict__ sm) {
    int p = blockIdx.x * blockDim.x + threadIdx.x;
    if (p >= HWN) return;
    float v[CC];
    #pragma unroll
    for (int c = 0; c < CC; ++c) v[c] = q[c*HWN + p];
    float mx = v[0];
    #pragma unroll
    for (int c = 1; c < CC; ++c) mx = fmaxf(mx, v[c]);
    float s = 0.f;
    #pragma unroll
    for (int c = 0; c < CC; ++c) { v[c] = expf(v[c] - mx); s += v[c]; }
    float inv = 1.0f / s;
    #pragma unroll
    for (int c = 0; c < CC; ++c) sm[c*HWN + p] = v[c] * inv;
}

__global__ void k_zero(float* sums) {
    int t = threadIdx.x;
    if (t < 3*CC) sums[t] = 0.f;
}

// clique reductions: sums[c]      = sum_{spm==idx}   exp(q[c]) - 1
//                    sums[C+c]    = sum_{spm==idx}   exp(A_np[c]) - 1
//                    sums[2C+c]   = sum_{spm==idx+1} exp(q[c]) - 1
__global__ void k_reduce(const float* __restrict__ q,
                         const int* __restrict__ spmT,
                         const int* __restrict__ spidx, int iter,
                         float* __restrict__ sums) {
    int p = blockIdx.x * blockDim.x + threadIdx.x;
    if (p >= HWN) return;
    int sidx = spidx[iter];
    int s = spmT[p];
    bool c1 = (s == sidx), c2 = (s == sidx + 1);
    if (!c1 && !c2) return;
    float v[CC];
    #pragma unroll
    for (int c = 0; c < CC; ++c) v[c] = q[c*HWN + p];
    if (c1) {
        float mx = v[0];
        #pragma unroll
        for (int c = 1; c < CC; ++c) mx = fmaxf(mx, v[c]);
        #pragma unroll
        for (int c = 0; c < CC; ++c) {
            atomicAdd(&sums[c], expf(v[c]) - 1.0f);
            float a = v[c] + mx - ((v[c] == mx) ? v[c] : 0.0f);
            atomicAdd(&sums[CC + c], expf(a) - 1.0f);
        }
    } else {
        #pragma unroll
        for (int c = 0; c < CC; ++c) atomicAdd(&sums[2*CC + c], expf(v[c]) - 1.0f);
    }
}

// lse[i] = log(HW + sums[i])   (all unmasked pixels contribute exp(0)=1)
__global__ void k_lse(const float* __restrict__ sums, float* __restrict__ lse) {
    int t = threadIdx.x;
    if (t < 3*CC) lse[t] = logf((float)HWN + sums[t]);
}

// ---------------------------------------------------------------------------
// q = u - (M1@spatial_out + M2@bilateral_out) - combined_update(q)
// ---------------------------------------------------------------------------
__global__ void k_update(const float* __restrict__ un,
                         const float* __restrict__ spo,
                         const float* __restrict__ blo,
                         const float* __restrict__ M1g,
                         const float* __restrict__ M2g,
                         const float* __restrict__ lseg,
                         const float* __restrict__ lwg,
                         const float* __restrict__ hwg,
                         const int* __restrict__ spmT,
                         const int* __restrict__ spidx, int iter,
                         float* __restrict__ q,
                         float* __restrict__ out, int last) {
    __shared__ float sM1[CC*CC], sM2[CC*CC], slse[3*CC], slw[3*CC], shw[3];
    for (int t = threadIdx.x; t < CC*CC; t += blockDim.x) { sM1[t] = M1g[t]; sM2[t] = M2g[t]; }
    if (threadIdx.x < 3*CC) { slse[threadIdx.x] = lseg[threadIdx.x]; slw[threadIdx.x] = lwg[threadIdx.x]; }
    if (threadIdx.x < 3) shw[threadIdx.x] = hwg[threadIdx.x];
    __syncthreads();
    int p = blockIdx.x * blockDim.x + threadIdx.x;
    if (p >= HWN) return;
    int sidx = spidx[iter];
    int s = spmT[p];
    float f1 = (s == sidx)     ? 1.f : 0.f;
    float f2 = (s == sidx + 1) ? 1.f : 0.f;

    float pair[CC];
    #pragma unroll
    for (int c = 0; c < CC; ++c) pair[c] = 0.f;
    #pragma unroll
    for (int k = 0; k < CC; ++k) {
        float sv = spo[k*HWN + p];
        float bv = blo[k*HWN + p];
        #pragma unroll
        for (int c = 0; c < CC; ++c) pair[c] += sM1[c*CC + k] * sv + sM2[c*CC + k] * bv;
    }

    float v[CC];
    #pragma unroll
    for (int c = 0; c < CC; ++c) v[c] = q[c*HWN + p];
    float mx = v[0];
    #pragma unroll
    for (int c = 1; c < CC; ++c) mx = fmaxf(mx, v[c]);

    float hw0 = shw[0], hw1 = shw[1], hw2 = shw[2];
    #pragma unroll
    for (int c = 0; c < CC; ++c) {
        float qv = v[c];
        float qmod = qv + ((qv == 0.f) ? 1.f : 0.f);
        float anp = f1 * (qv + mx) - ((f1 != 0.f && qv == mx) ? qv : 0.f);
        float qst = anp + ((anp == 0.f) ? 1.f : 0.f);
        float p1 = f1 * slse[c];
        float p2 = f1 * slse[CC + c];
        float p3 = p1 + f2 * slse[2*CC + c];
        float ft1 = p1 / qmod;
        float ft2 = p2 / qst;
        float ft3 = p3 / qmod;
        float cru = slw[c]*ft1        + hw0*(1.f - ft1)
                  + slw[CC + c]*ft2   + hw1*(1.f - ft2)
                  + slw[2*CC + c]*ft3 + hw2*(1.f - ft3);
        float qn = un[p*CC + c] - pair[c] - cru;
        q[c*HWN + p] = qn;
        if (last) out[p*CC + c] = qn;
    }
}

// ---------------------------------------------------------------------------
extern "C" void kernel_launch(void* const* d_in, const int* in_sizes, int n_in,
                              void* d_out, int out_size, void* d_ws, size_t ws_size,
                              hipStream_t stream) {
    const float* un    = (const float*)d_in[0];
    const float* rgb   = (const float*)d_in[1];
    const int*   spin  = (const int*)  d_in[2];
    const int*   spidx = (const int*)  d_in[3];
    const float* skw   = (const float*)d_in[4];
    const float* bkw   = (const float*)d_in[5];
    const float* lw    = (const float*)d_in[6];
    const float* hwv   = (const float*)d_in[7];
    const float* cm    = (const float*)d_in[8];
    float* out = (float*)d_out;

    float* ws = (float*)d_ws;
    float* q     = ws;
    float* a     = ws + (size_t)CHW;       // sm, later spatial_out
    float* ts    = ws + (size_t)2*CHW;
    float* tb    = ws + (size_t)3*CHW;
    float* b     = ws + (size_t)4*CHW;     // bilateral_out
    float* guide = ws + (size_t)5*CHW;
    float* snorm = guide + HWN;
    float* bnorm = snorm + HWN;
    int*   spmT  = (int*)(bnorm + HWN);
    float* M1    = bnorm + 2*(size_t)HWN;  // right after spmT (HWN ints)
    float* M2    = M1 + CC*CC;
    float* kbuf  = M2 + CC*CC;
    float* sums  = kbuf + 2*KS;
    float* lse   = sums + 3*CC;

    dim3 blk(256);
    int gpix  = HWN / 256;                 // 1024 blocks
    int gcpix = (CHW + 255) / 256;         // 21504 blocks

    k_init_small<<<1, 512, 0, stream>>>(cm, skw, bkw, M1, M2, kbuf);
    k_init_maps<<<gpix, blk, 0, stream>>>(rgb, spin, un, guide, spmT, q);
    // norms (channel-independent): blur(1) and blur(guide)
    k_vblur<<<gpix, blk, 0, stream>>>(nullptr, guide, ts, tb, kbuf, 1);
    k_hblur<<<gpix, blk, 0, stream>>>(ts, tb, snorm, bnorm, nullptr, nullptr, kbuf, 1);

    for (int it = 0; it < NITER; ++it) {
        int last = (it == NITER - 1) ? 1 : 0;
        k_zero<<<1, 64, 0, stream>>>(sums);
        k_softmax<<<gpix, blk, 0, stream>>>(q, a);
        k_vblur<<<gcpix, blk, 0, stream>>>(a, guide, ts, tb, kbuf, CC);
        k_hblur<<<gcpix, blk, 0, stream>>>(ts, tb, a, b, snorm, bnorm, kbuf, CC);
        k_reduce<<<gpix, blk, 0, stream>>>(q, spmT, spidx, it, sums);
        k_lse<<<1, 64, 0, stream>>>(sums, lse);
        k_update<<<gpix, blk, 0, stream>>>(un, a, b, M1, M2, lse, lw, hwv,
                                           spmT, spidx, it, q, out, last);
    }
}

// Round 2
// 3186.334 us; speedup vs baseline: 1.1210x; 1.1210x over previous
//
#include <hip/hip_runtime.h>
#include <math.h>

#define CC 21
#define HH 512
#define WW 512
#define HWN (HH*WW)
#define CHW (CC*HWN)
#define RAD 7
#define KS 15
#define NITER 5

// ---------------------------------------------------------------------------
// init: M1 = CM@SKW, M2 = CM@BKW  (21x21 each), gaussian taps (sigma 3, 10),
// zero the per-iteration clique sums (5 iters x 3*CC)
// ---------------------------------------------------------------------------
__global__ void k_init_small(const float* __restrict__ cm,
                             const float* __restrict__ skw,
                             const float* __restrict__ bkw,
                             float* __restrict__ M1, float* __restrict__ M2,
                             float* __restrict__ kbuf,
                             float* __restrict__ sums) {
    int t = threadIdx.x;
    if (t < CC*CC) {
        int i = t / CC, j = t % CC;
        float a = 0.f, b = 0.f;
        for (int k = 0; k < CC; ++k) {
            a += cm[i*CC+k] * skw[k*CC+j];
            b += cm[i*CC+k] * bkw[k*CC+j];
        }
        M1[t] = a; M2[t] = b;
    }
    if (t < NITER*3*CC) sums[t] = 0.f;
    if (t == CC*CC) {
        float w3[KS], w10[KS];
        float s3 = 0.f, s10 = 0.f;
        for (int i = 0; i < KS; ++i) {
            float x = (float)(i - RAD);
            w3[i]  = expf(-0.5f * (x/3.0f)  * (x/3.0f));
            w10[i] = expf(-0.5f * (x/10.0f) * (x/10.0f));
            s3 += w3[i]; s10 += w10[i];
        }
        for (int i = 0; i < KS; ++i) {
            kbuf[i]      = w3[i]  / s3;
            kbuf[KS + i] = w10[i] / s10;
        }
    }
}

// guide(h,w), spmT(h,w) = sp_map[w][h], q(c,h,w) = unaries[h][w][c]
__global__ void k_init_maps(const float* __restrict__ rgb,
                            const int* __restrict__ spin,
                            const float* __restrict__ un,
                            float* __restrict__ guide,
                            int* __restrict__ spmT,
                            float* __restrict__ q) {
    int p = blockIdx.x * blockDim.x + threadIdx.x;
    if (p >= HWN) return;
    int h = p / WW, w = p - h*WW;
    float r = rgb[p*3+0] * (1.0f/255.0f);
    float g = rgb[p*3+1] * (1.0f/255.0f);
    float b = rgb[p*3+2] * (1.0f/255.0f);
    guide[p] = expf(-0.5f * (r*r + g*g + b*b) / 9.0f);   // theta_beta^2 = 9
    spmT[p] = spin[w*HH + h];
    #pragma unroll
    for (int c = 0; c < CC; ++c) q[c*HWN + p] = un[p*CC + c];
}

// ---------------------------------------------------------------------------
// vertical blur (fused spatial sigma=3 + bilateral sigma=10 with guide premul)
// in == nullptr means input === 1.0  (norm computation)
// ---------------------------------------------------------------------------
__global__ void k_vblur(const float* __restrict__ in,
                        const float* __restrict__ guide,
                        float* __restrict__ outs, float* __restrict__ outb,
                        const float* __restrict__ kbuf, int nc) {
    __shared__ float k3[KS], k10[KS];
    if (threadIdx.x < KS) {
        k3[threadIdx.x]  = kbuf[threadIdx.x];
        k10[threadIdx.x] = kbuf[KS + threadIdx.x];
    }
    __syncthreads();
    int idx = blockIdx.x * blockDim.x + threadIdx.x;
    if (idx >= nc * HWN) return;
    int c = idx / HWN, p = idx - c*HWN;
    int h = p / WW, w = p - h*WW;
    float as = 0.f, ab = 0.f;
    #pragma unroll
    for (int d = 0; d < KS; ++d) {
        int hh = h + d - RAD;
        if (hh >= 0 && hh < HH) {
            int pp = hh*WW + w;
            float v = in ? in[c*HWN + pp] : 1.0f;
            as += k3[d] * v;
            ab += k10[d] * (v * guide[pp]);
        }
    }
    outs[idx] = as;
    outb[idx] = ab;
}

// horizontal blur; optional division by norms (null -> no division)
__global__ void k_hblur(const float* __restrict__ ins,
                        const float* __restrict__ inb,
                        float* __restrict__ outs, float* __restrict__ outb,
                        const float* __restrict__ snorm,
                        const float* __restrict__ bnorm,
                        const float* __restrict__ kbuf, int nc) {
    __shared__ float k3[KS], k10[KS];
    if (threadIdx.x < KS) {
        k3[threadIdx.x]  = kbuf[threadIdx.x];
        k10[threadIdx.x] = kbuf[KS + threadIdx.x];
    }
    __syncthreads();
    int idx = blockIdx.x * blockDim.x + threadIdx.x;
    if (idx >= nc * HWN) return;
    int c = idx / HWN, p = idx - c*HWN;
    int h = p / WW, w = p - h*WW;
    float as = 0.f, ab = 0.f;
    int rowbase = c*HWN + h*WW;
    #pragma unroll
    for (int d = 0; d < KS; ++d) {
        int ww = w + d - RAD;
        if (ww >= 0 && ww < WW) {
            as += k3[d]  * ins[rowbase + ww];
            ab += k10[d] * inb[rowbase + ww];
        }
    }
    if (snorm) { as /= snorm[p]; ab /= bnorm[p]; }
    outs[idx] = as;
    outb[idx] = ab;
}

// ---------------------------------------------------------------------------
// channel softmax per pixel + fused clique reductions over the same q read:
//   sums[c]      = sum_{spm==idx}   exp(q[c]) - 1
//   sums[C+c]    = sum_{spm==idx}   exp(A_np[c]) - 1
//   sums[2C+c]   = sum_{spm==idx+1} exp(q[c]) - 1
// ---------------------------------------------------------------------------
__global__ void __launch_bounds__(256, 2)
k_softmax_reduce(const float* __restrict__ q, float* __restrict__ sm,
                 const int* __restrict__ spmT,
                 const int* __restrict__ spidx, int iter,
                 float* __restrict__ sums) {
    int p = blockIdx.x * blockDim.x + threadIdx.x;
    if (p >= HWN) return;
    float v[CC];
    #pragma unroll
    for (int c = 0; c < CC; ++c) v[c] = q[c*HWN + p];
    float mx = v[0];
    #pragma unroll
    for (int c = 1; c < CC; ++c) mx = fmaxf(mx, v[c]);
    float e[CC];
    float s = 0.f;
    #pragma unroll
    for (int c = 0; c < CC; ++c) { e[c] = expf(v[c] - mx); s += e[c]; }
    float inv = 1.0f / s;
    #pragma unroll
    for (int c = 0; c < CC; ++c) sm[c*HWN + p] = e[c] * inv;

    int sidx = spidx[iter];
    int sv = spmT[p];
    bool c1 = (sv == sidx), c2 = (sv == sidx + 1);
    if (c1) {
        float emx = expf(mx);
        #pragma unroll
        for (int c = 0; c < CC; ++c) {
            float ev = e[c] * emx;                  // exp(v[c])
            atomicAdd(&sums[c], ev - 1.0f);
            // A_np = v + mx, except when v==mx it is just mx (v+mx-v)
            float ea = (v[c] == mx) ? emx : ev * emx;   // exp(A_np)
            atomicAdd(&sums[CC + c], ea - 1.0f);
        }
    } else if (c2) {
        float emx = expf(mx);
        #pragma unroll
        for (int c = 0; c < CC; ++c)
            atomicAdd(&sums[2*CC + c], e[c] * emx - 1.0f);
    }
}

// ---------------------------------------------------------------------------
// q = u - (M1@spatial_out + M2@bilateral_out) - combined_update(q)
// lse computed in-kernel from sums: lse[i] = log(HWN + sums[i])
// ---------------------------------------------------------------------------
__global__ void __launch_bounds__(256, 2)
k_update(const float* __restrict__ un,
         const float* __restrict__ spo,
         const float* __restrict__ blo,
         const float* __restrict__ M1g,
         const float* __restrict__ M2g,
         const float* __restrict__ sums,
         const float* __restrict__ lwg,
         const float* __restrict__ hwg,
         const int* __restrict__ spmT,
         const int* __restrict__ spidx, int iter,
         float* __restrict__ q,
         float* __restrict__ out, int last) {
    __shared__ float sM1[CC*CC], sM2[CC*CC], slse[3*CC], slw[3*CC], shw[3];
    for (int t = threadIdx.x; t < CC*CC; t += blockDim.x) { sM1[t] = M1g[t]; sM2[t] = M2g[t]; }
    if (threadIdx.x < 3*CC) {
        slse[threadIdx.x] = logf((float)HWN + sums[threadIdx.x]);
        slw[threadIdx.x] = lwg[threadIdx.x];
    }
    if (threadIdx.x < 3) shw[threadIdx.x] = hwg[threadIdx.x];
    __syncthreads();
    int p = blockIdx.x * blockDim.x + threadIdx.x;
    if (p >= HWN) return;
    int sidx = spidx[iter];
    int s = spmT[p];
    float f1 = (s == sidx)     ? 1.f : 0.f;
    float f2 = (s == sidx + 1) ? 1.f : 0.f;

    float pair[CC];
    #pragma unroll
    for (int c = 0; c < CC; ++c) pair[c] = 0.f;
    #pragma unroll
    for (int k = 0; k < CC; ++k) {
        float sv = spo[k*HWN + p];
        float bv = blo[k*HWN + p];
        #pragma unroll
        for (int c = 0; c < CC; ++c) pair[c] += sM1[c*CC + k] * sv + sM2[c*CC + k] * bv;
    }

    float v[CC];
    #pragma unroll
    for (int c = 0; c < CC; ++c) v[c] = q[c*HWN + p];
    float mx = v[0];
    #pragma unroll
    for (int c = 1; c < CC; ++c) mx = fmaxf(mx, v[c]);

    float hw0 = shw[0], hw1 = shw[1], hw2 = shw[2];
    #pragma unroll
    for (int c = 0; c < CC; ++c) {
        float qv = v[c];
        float qmod = qv + ((qv == 0.f) ? 1.f : 0.f);
        float anp = f1 * (qv + mx) - ((f1 != 0.f && qv == mx) ? qv : 0.0f);
        float qst = anp + ((anp == 0.f) ? 1.f : 0.f);
        float p1 = f1 * slse[c];
        float p2 = f1 * slse[CC + c];
        float p3 = p1 + f2 * slse[2*CC + c];
        float ft1 = p1 / qmod;
        float ft2 = p2 / qst;
        float ft3 = p3 / qmod;
        float cru = slw[c]*ft1        + hw0*(1.f - ft1)
                  + slw[CC + c]*ft2   + hw1*(1.f - ft2)
                  + slw[2*CC + c]*ft3 + hw2*(1.f - ft3);
        float qn = un[p*CC + c] - pair[c] - cru;
        q[c*HWN + p] = qn;
        if (last) out[p*CC + c] = qn;
    }
}

// ---------------------------------------------------------------------------
extern "C" void kernel_launch(void* const* d_in, const int* in_sizes, int n_in,
                              void* d_out, int out_size, void* d_ws, size_t ws_size,
                              hipStream_t stream) {
    const float* un    = (const float*)d_in[0];
    const float* rgb   = (const float*)d_in[1];
    const int*   spin  = (const int*)  d_in[2];
    const int*   spidx = (const int*)  d_in[3];
    const float* skw   = (const float*)d_in[4];
    const float* bkw   = (const float*)d_in[5];
    const float* lw    = (const float*)d_in[6];
    const float* hwv   = (const float*)d_in[7];
    const float* cm    = (const float*)d_in[8];
    float* out = (float*)d_out;

    float* ws = (float*)d_ws;
    float* q     = ws;
    float* a     = ws + (size_t)CHW;       // sm, later spatial_out
    float* ts    = ws + (size_t)2*CHW;
    float* tb    = ws + (size_t)3*CHW;
    float* b     = ws + (size_t)4*CHW;     // bilateral_out
    float* guide = ws + (size_t)5*CHW;
    float* snorm = guide + HWN;
    float* bnorm = snorm + HWN;
    int*   spmT  = (int*)(bnorm + HWN);
    float* M1    = bnorm + 2*(size_t)HWN;  // right after spmT (HWN ints)
    float* M2    = M1 + CC*CC;
    float* kbuf  = M2 + CC*CC;
    float* sums  = kbuf + 2*KS;            // NITER * 3*CC floats

    dim3 blk(256);
    int gpix  = HWN / 256;                 // 1024 blocks
    int gcpix = (CHW + 255) / 256;         // 21504 blocks

    k_init_small<<<1, 512, 0, stream>>>(cm, skw, bkw, M1, M2, kbuf, sums);
    k_init_maps<<<gpix, blk, 0, stream>>>(rgb, spin, un, guide, spmT, q);
    // norms (channel-independent): blur(1) and blur(guide)
    k_vblur<<<gpix, blk, 0, stream>>>(nullptr, guide, ts, tb, kbuf, 1);
    k_hblur<<<gpix, blk, 0, stream>>>(ts, tb, snorm, bnorm, nullptr, nullptr, kbuf, 1);

    for (int it = 0; it < NITER; ++it) {
        int last = (it == NITER - 1) ? 1 : 0;
        float* su = sums + it*3*CC;
        k_softmax_reduce<<<gpix, blk, 0, stream>>>(q, a, spmT, spidx, it, su);
        k_vblur<<<gcpix, blk, 0, stream>>>(a, guide, ts, tb, kbuf, CC);
        k_hblur<<<gcpix, blk, 0, stream>>>(ts, tb, a, b, snorm, bnorm, kbuf, CC);
        k_update<<<gpix, blk, 0, stream>>>(un, a, b, M1, M2, su, lw, hwv,
                                           spmT, spidx, it, q, out, last);
    }
}

// Round 3
// 963.315 us; speedup vs baseline: 3.7080x; 3.3077x over previous
//
#include <hip/hip_runtime.h>
#include <math.h>

#define CC 21
#define HH 512
#define WW 512
#define HWN (HH*WW)
#define CHW (CC*HWN)
#define RAD 7
#define KS 15
#define NITER 5
#define NBKT 16

#define TW 128
#define TH 32
#define TWH (TW + 2*RAD)   // 142
#define LSTR 148           // padded LDS row stride (floats) — breaks 8-way bank conflict

// ---------------------------------------------------------------------------
// init: M1t[k][c] = (CM@SKW)[c][k], M2t[k][c] = (CM@BKW)[c][k], taps, zero sums
// ---------------------------------------------------------------------------
__global__ void k_init_small(const float* __restrict__ cm,
                             const float* __restrict__ skw,
                             const float* __restrict__ bkw,
                             float* __restrict__ M1t, float* __restrict__ M2t,
                             float* __restrict__ kbuf,
                             float* __restrict__ sums) {
    int t = threadIdx.x;
    if (t < CC*CC) {
        int k = t / CC, c = t % CC;
        float a = 0.f, b = 0.f;
        for (int m = 0; m < CC; ++m) {
            a += cm[c*CC+m] * skw[m*CC+k];
            b += cm[c*CC+m] * bkw[m*CC+k];
        }
        M1t[t] = a; M2t[t] = b;
    }
    for (int i = t; i < NITER*NBKT*64; i += blockDim.x) sums[i] = 0.f;
    if (t == CC*CC) {
        float w3[KS], w10[KS];
        float s3 = 0.f, s10 = 0.f;
        for (int i = 0; i < KS; ++i) {
            float x = (float)(i - RAD);
            w3[i]  = expf(-0.5f * (x/3.0f)  * (x/3.0f));
            w10[i] = expf(-0.5f * (x/10.0f) * (x/10.0f));
            s3 += w3[i]; s10 += w10[i];
        }
        for (int i = 0; i < KS; ++i) {
            kbuf[i]      = w3[i]  / s3;
            kbuf[KS + i] = w10[i] / s10;
        }
    }
}

// ---------------------------------------------------------------------------
// guide, spmT, q0 = transpose(un), sm0 = softmax(q0), clique sums for iter 0
// ---------------------------------------------------------------------------
__global__ void __launch_bounds__(256, 1)
k_init_maps(const float* __restrict__ rgb,
            const int* __restrict__ spin,
            const float* __restrict__ un,
            float* __restrict__ guide,
            int* __restrict__ spmT,
            float* __restrict__ q,
            float* __restrict__ sm,
            const int* __restrict__ spidx,
            float* __restrict__ sums0) {
    int p = blockIdx.x * blockDim.x + threadIdx.x;
    int h = p / WW, w = p - h*WW;
    float r = rgb[p*3+0] * (1.0f/255.0f);
    float g = rgb[p*3+1] * (1.0f/255.0f);
    float b = rgb[p*3+2] * (1.0f/255.0f);
    guide[p] = expf(-0.5f * (r*r + g*g + b*b) / 9.0f);   // theta_beta^2 = 9
    int s = spin[w*HH + h];
    spmT[p] = s;
    float v[CC];
    #pragma unroll
    for (int c = 0; c < CC; ++c) { v[c] = un[p*CC + c]; q[c*HWN + p] = v[c]; }
    float mx = v[0];
    #pragma unroll
    for (int c = 1; c < CC; ++c) mx = fmaxf(mx, v[c]);
    float e[CC], ssum = 0.f;
    #pragma unroll
    for (int c = 0; c < CC; ++c) { e[c] = expf(v[c] - mx); ssum += e[c]; }
    float inv = 1.0f / ssum;
    #pragma unroll
    for (int c = 0; c < CC; ++c) sm[c*HWN + p] = e[c] * inv;

    int sidx = spidx[0];
    bool c1 = (s == sidx), c2 = (s == sidx + 1);
    if (c1 || c2) {
        float* bkt = sums0 + (blockIdx.x & (NBKT-1)) * 64;
        float emx = expf(mx);
        if (c1) {
            #pragma unroll
            for (int c = 0; c < CC; ++c) {
                float ev = e[c] * emx;                       // exp(q)
                atomicAdd(&bkt[c], ev - 1.0f);
                float ea = (v[c] == mx) ? emx : ev * emx;    // exp(A_np)
                atomicAdd(&bkt[CC + c], ea - 1.0f);
            }
        } else {
            #pragma unroll
            for (int c = 0; c < CC; ++c) atomicAdd(&bkt[2*CC + c], e[c] * emx - 1.0f);
        }
    }
}

// ---------------------------------------------------------------------------
// fused separable blur (spatial sigma=3 AND bilateral sigma=10 w/ guide premul)
// tile 128x32, v-pass in registers, h-pass from LDS.
// norm_mode: input == 1.0, writes reciprocal norms; else divides via stored recips.
// ---------------------------------------------------------------------------
__global__ void __launch_bounds__(256, 2)
k_blur(const float* __restrict__ in,       // null in norm mode
       const float* __restrict__ guide,
       float* __restrict__ outs, float* __restrict__ outb,
       const float* __restrict__ rsn, const float* __restrict__ rbn,
       const float* __restrict__ kbuf, int norm_mode) {
    __shared__ float vbs[TH][LSTR];
    __shared__ float vbb[TH][LSTR];
    __shared__ float k3s[KS], k10s[KS];
    int t = threadIdx.x;
    if (t < KS) { k3s[t] = kbuf[t]; k10s[t] = kbuf[KS + t]; }
    __syncthreads();

    int c  = blockIdx.z;
    int x0 = blockIdx.x * TW;
    int y0 = blockIdx.y * TH;
    const float* base = in ? (in + (size_t)c*HWN) : nullptr;

    if (t < TWH) {
        int xg = x0 - RAD + t;
        bool xok = (xg >= 0 && xg < WW);
        float ws_[KS], wb_[KS];
        #pragma unroll
        for (int i = 0; i < KS-1; ++i) {
            int yg = y0 - RAD + i;
            bool ok = xok && (yg >= 0) && (yg < HH);
            float v = 0.f, g = 0.f;
            if (ok) { g = guide[yg*WW + xg]; v = base ? base[yg*WW + xg] : 1.0f; }
            ws_[i] = v; wb_[i] = v * g;
        }
        #pragma unroll
        for (int y = 0; y < TH; ++y) {
            int yg = y0 + y + RAD;
            bool ok = xok && (yg < HH);
            float v = 0.f, g = 0.f;
            if (ok) { g = guide[yg*WW + xg]; v = base ? base[yg*WW + xg] : 1.0f; }
            ws_[(KS-1+y)%KS] = v; wb_[(KS-1+y)%KS] = v * g;
            float as = 0.f, ab = 0.f;
            #pragma unroll
            for (int d = 0; d < KS; ++d) {
                as += k3s[d]  * ws_[(y+d)%KS];
                ab += k10s[d] * wb_[(y+d)%KS];
            }
            vbs[y][t] = as; vbb[y][t] = ab;
        }
    }
    __syncthreads();

    // h-pass: 256 threads = 32 rows x 8 groups of 16 consecutive outputs
    int oy = t >> 3;
    int xs = (t & 7) * 16;
    int gy = y0 + oy;
    int rowp  = gy*WW + x0 + xs;
    size_t ob = (size_t)c*HWN + rowp;

    float w[30], res[16];
    #pragma unroll
    for (int i = 0; i < 30; ++i) w[i] = vbs[oy][xs + i];
    #pragma unroll
    for (int j = 0; j < 16; ++j) {
        float a = 0.f;
        #pragma unroll
        for (int d = 0; d < KS; ++d) a += k3s[d] * w[j + d];
        res[j] = a;
    }
    if (norm_mode) {
        #pragma unroll
        for (int j = 0; j < 16; ++j) outs[rowp + j] = 1.0f / res[j];
    } else {
        #pragma unroll
        for (int j = 0; j < 16; ++j) outs[ob + j] = res[j] * rsn[rowp + j];
    }

    #pragma unroll
    for (int i = 0; i < 30; ++i) w[i] = vbb[oy][xs + i];
    #pragma unroll
    for (int j = 0; j < 16; ++j) {
        float a = 0.f;
        #pragma unroll
        for (int d = 0; d < KS; ++d) a += k10s[d] * w[j + d];
        res[j] = a;
    }
    if (norm_mode) {
        #pragma unroll
        for (int j = 0; j < 16; ++j) outb[rowp + j] = 1.0f / res[j];
    } else {
        #pragma unroll
        for (int j = 0; j < 16; ++j) outb[ob + j] = res[j] * rbn[rowp + j];
    }
}

// ---------------------------------------------------------------------------
// q_{i+1} = u - (M1@spo + M2@blo) - cru(q_i); then (unless last) softmax and
// clique reduction for iteration i+1, fused.
// ---------------------------------------------------------------------------
__global__ void __launch_bounds__(256, 1)
k_update(const float* __restrict__ un,
         const float* __restrict__ spo,
         const float* __restrict__ blo,
         const float* __restrict__ M1t,   // [k][c]
         const float* __restrict__ M2t,
         const float* __restrict__ sums_cur,
         float* __restrict__ sums_next,
         const float* __restrict__ lwg,
         const float* __restrict__ hwg,
         const int* __restrict__ spmT,
         const int* __restrict__ spidx, int iter,
         float* __restrict__ q,
         float* __restrict__ sm,
         float* __restrict__ out, int last) {
    __shared__ float slse[3*CC], slw[3*CC], shw[3];
    if (threadIdx.x < 3*CC) {
        float s = 0.f;
        #pragma unroll
        for (int b = 0; b < NBKT; ++b) s += sums_cur[b*64 + threadIdx.x];
        slse[threadIdx.x] = logf((float)HWN + s);
        slw[threadIdx.x] = lwg[threadIdx.x];
    }
    if (threadIdx.x < 3) shw[threadIdx.x] = hwg[threadIdx.x];
    __syncthreads();

    int p = blockIdx.x * blockDim.x + threadIdx.x;
    int sidx = spidx[iter];
    int s = spmT[p];
    float f1 = (s == sidx)     ? 1.f : 0.f;
    float f2 = (s == sidx + 1) ? 1.f : 0.f;

    float acc[CC];
    #pragma unroll
    for (int c = 0; c < CC; ++c) acc[c] = 0.f;
    #pragma unroll
    for (int k = 0; k < CC; ++k) {
        float sv = spo[k*HWN + p];
        float bv = blo[k*HWN + p];
        #pragma unroll
        for (int c = 0; c < CC; ++c)
            acc[c] += M1t[k*CC + c] * sv + M2t[k*CC + c] * bv;
    }

    float v[CC];
    #pragma unroll
    for (int c = 0; c < CC; ++c) v[c] = q[c*HWN + p];
    float mx = v[0];
    #pragma unroll
    for (int c = 1; c < CC; ++c) mx = fmaxf(mx, v[c]);

    float hw0 = shw[0], hw1 = shw[1], hw2 = shw[2];
    #pragma unroll
    for (int c = 0; c < CC; ++c) {
        float qv = v[c];
        float qmod = qv + ((qv == 0.f) ? 1.f : 0.f);
        float anp = f1 * (qv + mx) - ((f1 != 0.f && qv == mx) ? qv : 0.f);
        float qst = anp + ((anp == 0.f) ? 1.f : 0.f);
        float p1 = f1 * slse[c];
        float p2 = f1 * slse[CC + c];
        float p3 = p1 + f2 * slse[2*CC + c];
        float ft1 = p1 / qmod;
        float ft2 = p2 / qst;
        float ft3 = p3 / qmod;
        float cru = slw[c]*ft1        + hw0*(1.f - ft1)
                  + slw[CC + c]*ft2   + hw1*(1.f - ft2)
                  + slw[2*CC + c]*ft3 + hw2*(1.f - ft3);
        float qn = un[p*CC + c] - acc[c] - cru;
        q[c*HWN + p] = qn;
        acc[c] = qn;
        if (last) out[p*CC + c] = qn;
    }

    if (!last) {
        float mx2 = acc[0];
        #pragma unroll
        for (int c = 1; c < CC; ++c) mx2 = fmaxf(mx2, acc[c]);
        float e[CC], ssum = 0.f;
        #pragma unroll
        for (int c = 0; c < CC; ++c) { e[c] = expf(acc[c] - mx2); ssum += e[c]; }
        float inv = 1.0f / ssum;
        #pragma unroll
        for (int c = 0; c < CC; ++c) sm[c*HWN + p] = e[c] * inv;

        int sidx2 = spidx[iter + 1];
        bool c1 = (s == sidx2), c2 = (s == sidx2 + 1);
        if (c1 || c2) {
            float* bkt = sums_next + (blockIdx.x & (NBKT-1)) * 64;
            float emx = expf(mx2);
            if (c1) {
                #pragma unroll
                for (int c = 0; c < CC; ++c) {
                    float ev = e[c] * emx;
                    atomicAdd(&bkt[c], ev - 1.0f);
                    float ea = (acc[c] == mx2) ? emx : ev * emx;
                    atomicAdd(&bkt[CC + c], ea - 1.0f);
                }
            } else {
                #pragma unroll
                for (int c = 0; c < CC; ++c) atomicAdd(&bkt[2*CC + c], e[c] * emx - 1.0f);
            }
        }
    }
}

// ---------------------------------------------------------------------------
extern "C" void kernel_launch(void* const* d_in, const int* in_sizes, int n_in,
                              void* d_out, int out_size, void* d_ws, size_t ws_size,
                              hipStream_t stream) {
    const float* un    = (const float*)d_in[0];
    const float* rgb   = (const float*)d_in[1];
    const int*   spin  = (const int*)  d_in[2];
    const int*   spidx = (const int*)  d_in[3];
    const float* skw   = (const float*)d_in[4];
    const float* bkw   = (const float*)d_in[5];
    const float* lw    = (const float*)d_in[6];
    const float* hwv   = (const float*)d_in[7];
    const float* cm    = (const float*)d_in[8];
    float* out = (float*)d_out;

    float* ws = (float*)d_ws;
    float* q     = ws;
    float* sm    = ws + (size_t)CHW;
    float* a     = ws + (size_t)2*CHW;     // spatial_out
    float* b     = ws + (size_t)3*CHW;     // bilateral_out
    float* guide = ws + (size_t)4*CHW;
    float* rsn   = guide + HWN;            // reciprocal spatial norm
    float* rbn   = rsn + HWN;
    int*   spmT  = (int*)(rbn + HWN);
    float* M1t   = rbn + 2*(size_t)HWN;    // after spmT (HWN ints)
    float* M2t   = M1t + CC*CC;
    float* kbuf  = M2t + CC*CC;
    float* sums  = kbuf + 2*KS;            // NITER * NBKT * 64 floats

    dim3 blk(256);
    int gpix = HWN / 256;                  // 1024 blocks
    dim3 gblur(WW/TW, HH/TH, CC);          // 4 x 16 x 21
    dim3 gnorm(WW/TW, HH/TH, 1);

    k_init_small<<<1, 512, 0, stream>>>(cm, skw, bkw, M1t, M2t, kbuf, sums);
    k_init_maps<<<gpix, blk, 0, stream>>>(rgb, spin, un, guide, spmT, q, sm,
                                          spidx, sums);
    k_blur<<<gnorm, blk, 0, stream>>>(nullptr, guide, rsn, rbn,
                                      nullptr, nullptr, kbuf, 1);

    for (int it = 0; it < NITER; ++it) {
        int last = (it == NITER - 1) ? 1 : 0;
        float* su  = sums + it*NBKT*64;
        float* sun = last ? nullptr : (sums + (it+1)*NBKT*64);
        k_blur<<<gblur, blk, 0, stream>>>(sm, guide, a, b, rsn, rbn, kbuf, 0);
        k_update<<<gpix, blk, 0, stream>>>(un, a, b, M1t, M2t, su, sun, lw, hwv,
                                           spmT, spidx, it, q, sm, out, last);
    }
}

// Round 4
// 547.893 us; speedup vs baseline: 6.5194x; 1.7582x over previous
//
#include <hip/hip_runtime.h>
#include <math.h>

#define CC 21
#define HH 512
#define WW 512
#define HWN (HH*WW)
#define CHW (CC*HWN)
#define RAD 7
#define KS 15
#define NITER 5
#define NBKT 16

#define TW 128
#define TH 32
#define TWH (TW + 2*RAD)   // 142
#define LSTR 148           // padded LDS row stride (floats)

#define FEXP(x) __expf(x)
#define FLOG(x) __logf(x)
#define FRCP(x) __builtin_amdgcn_rcpf(x)

// ---------------------------------------------------------------------------
// init: M1t[k][c] = (CM@SKW)[c][k], M2t[k][c] = (CM@BKW)[c][k], taps, zero
// sums, diagonality flag + diagonal extracts
// ---------------------------------------------------------------------------
__global__ void k_init_small(const float* __restrict__ cm,
                             const float* __restrict__ skw,
                             const float* __restrict__ bkw,
                             float* __restrict__ M1t, float* __restrict__ M2t,
                             float* __restrict__ d1, float* __restrict__ d2,
                             int* __restrict__ dflag,
                             float* __restrict__ kbuf,
                             float* __restrict__ sums) {
    int t = threadIdx.x;
    if (t < CC*CC) {
        int k = t / CC, c = t % CC;
        float a = 0.f, b = 0.f;
        for (int m = 0; m < CC; ++m) {
            a += cm[c*CC+m] * skw[m*CC+k];
            b += cm[c*CC+m] * bkw[m*CC+k];
        }
        M1t[t] = a; M2t[t] = b;
    }
    for (int i = t; i < NITER*NBKT*64; i += blockDim.x) sums[i] = 0.f;
    if (t == CC*CC) {
        float w3[KS], w10[KS];
        float s3 = 0.f, s10 = 0.f;
        for (int i = 0; i < KS; ++i) {
            float x = (float)(i - RAD);
            w3[i]  = expf(-0.5f * (x/3.0f)  * (x/3.0f));
            w10[i] = expf(-0.5f * (x/10.0f) * (x/10.0f));
            s3 += w3[i]; s10 += w10[i];
        }
        for (int i = 0; i < KS; ++i) {
            kbuf[i]      = w3[i]  / s3;
            kbuf[KS + i] = w10[i] / s10;
        }
    }
    __syncthreads();
    if (t == 0) {
        int dg = 1;
        for (int i = 0; i < CC*CC; ++i) {
            int k = i / CC, c = i % CC;
            if (k != c && (M1t[i] != 0.f || M2t[i] != 0.f)) { dg = 0; break; }
        }
        dflag[0] = dg;
    }
    if (t < CC) { d1[t] = M1t[t*CC + t]; d2[t] = M2t[t*CC + t]; }
}

// ---------------------------------------------------------------------------
// guide, spmT, q0 = transpose(un), sm0 = softmax(q0), clique sums for iter 0
// ---------------------------------------------------------------------------
__global__ void __launch_bounds__(256, 1)
k_init_maps(const float* __restrict__ rgb,
            const int* __restrict__ spin,
            const float* __restrict__ un,
            float* __restrict__ guide,
            int* __restrict__ spmT,
            float* __restrict__ q,
            float* __restrict__ sm,
            const int* __restrict__ spidx,
            float* __restrict__ sums0) {
    __shared__ float lun[256*CC];
    {
        const float4* src = (const float4*)(un + (size_t)blockIdx.x*(256*CC));
        float4* dst = (float4*)lun;
        for (int i = threadIdx.x; i < (256*CC)/4; i += 256) dst[i] = src[i];
    }
    __syncthreads();
    int p = blockIdx.x * blockDim.x + threadIdx.x;
    int h = p / WW, w = p - h*WW;
    float r = rgb[p*3+0] * (1.0f/255.0f);
    float g = rgb[p*3+1] * (1.0f/255.0f);
    float b = rgb[p*3+2] * (1.0f/255.0f);
    guide[p] = FEXP(-0.5f * (r*r + g*g + b*b) / 9.0f);   // theta_beta^2 = 9
    int s = spin[w*HH + h];
    spmT[p] = s;
    int tb = threadIdx.x * CC;
    float v[CC];
    #pragma unroll
    for (int c = 0; c < CC; ++c) { v[c] = lun[tb + c]; q[c*HWN + p] = v[c]; }
    float mx = v[0];
    #pragma unroll
    for (int c = 1; c < CC; ++c) mx = fmaxf(mx, v[c]);
    float e[CC], ssum = 0.f;
    #pragma unroll
    for (int c = 0; c < CC; ++c) { e[c] = FEXP(v[c] - mx); ssum += e[c]; }
    float inv = FRCP(ssum);
    #pragma unroll
    for (int c = 0; c < CC; ++c) sm[c*HWN + p] = e[c] * inv;

    int sidx = spidx[0];
    bool c1 = (s == sidx), c2 = (s == sidx + 1);
    if (c1 || c2) {
        float* bkt = sums0 + (blockIdx.x & (NBKT-1)) * 64;
        float emx = FEXP(mx);
        if (c1) {
            #pragma unroll
            for (int c = 0; c < CC; ++c) {
                float ev = e[c] * emx;                       // exp(q)
                atomicAdd(&bkt[c], ev - 1.0f);
                float ea = (v[c] == mx) ? emx : ev * emx;    // exp(A_np)
                atomicAdd(&bkt[CC + c], ea - 1.0f);
            }
        } else {
            #pragma unroll
            for (int c = 0; c < CC; ++c) atomicAdd(&bkt[2*CC + c], e[c] * emx - 1.0f);
        }
    }
}

// ---------------------------------------------------------------------------
// fused separable blur (spatial sigma=3 AND bilateral sigma=10 w/ guide premul)
// tile 128x32, v-pass in registers, h-pass from LDS.
// ---------------------------------------------------------------------------
__global__ void __launch_bounds__(256, 2)
k_blur(const float* __restrict__ in,       // null in norm mode
       const float* __restrict__ guide,
       float* __restrict__ outs, float* __restrict__ outb,
       const float* __restrict__ rsn, const float* __restrict__ rbn,
       const float* __restrict__ kbuf, int norm_mode) {
    __shared__ float vbs[TH][LSTR];
    __shared__ float vbb[TH][LSTR];
    __shared__ float k3s[KS], k10s[KS];
    int t = threadIdx.x;
    if (t < KS) { k3s[t] = kbuf[t]; k10s[t] = kbuf[KS + t]; }
    __syncthreads();

    int c  = blockIdx.z;
    int x0 = blockIdx.x * TW;
    int y0 = blockIdx.y * TH;
    const float* base = in ? (in + (size_t)c*HWN) : nullptr;

    if (t < TWH) {
        int xg = x0 - RAD + t;
        bool xok = (xg >= 0 && xg < WW);
        float ws_[KS], wb_[KS];
        #pragma unroll
        for (int i = 0; i < KS-1; ++i) {
            int yg = y0 - RAD + i;
            bool ok = xok && (yg >= 0) && (yg < HH);
            float v = 0.f, g = 0.f;
            if (ok) { g = guide[yg*WW + xg]; v = base ? base[yg*WW + xg] : 1.0f; }
            ws_[i] = v; wb_[i] = v * g;
        }
        #pragma unroll
        for (int y = 0; y < TH; ++y) {
            int yg = y0 + y + RAD;
            bool ok = xok && (yg < HH);
            float v = 0.f, g = 0.f;
            if (ok) { g = guide[yg*WW + xg]; v = base ? base[yg*WW + xg] : 1.0f; }
            ws_[(KS-1+y)%KS] = v; wb_[(KS-1+y)%KS] = v * g;
            float as = 0.f, ab = 0.f;
            #pragma unroll
            for (int d = 0; d < KS; ++d) {
                as += k3s[d]  * ws_[(y+d)%KS];
                ab += k10s[d] * wb_[(y+d)%KS];
            }
            vbs[y][t] = as; vbb[y][t] = ab;
        }
    }
    __syncthreads();

    // h-pass: 256 threads = 32 rows x 8 groups of 16 consecutive outputs
    int oy = t >> 3;
    int xs = (t & 7) * 16;
    int gy = y0 + oy;
    int rowp  = gy*WW + x0 + xs;
    size_t ob = (size_t)c*HWN + rowp;

    float w[30], res[16];
    #pragma unroll
    for (int i = 0; i < 30; ++i) w[i] = vbs[oy][xs + i];
    #pragma unroll
    for (int j = 0; j < 16; ++j) {
        float a = 0.f;
        #pragma unroll
        for (int d = 0; d < KS; ++d) a += k3s[d] * w[j + d];
        res[j] = a;
    }
    if (norm_mode) {
        #pragma unroll
        for (int j = 0; j < 16; ++j) outs[rowp + j] = 1.0f / res[j];
    } else {
        #pragma unroll
        for (int j = 0; j < 16; ++j) outs[ob + j] = res[j] * rsn[rowp + j];
    }

    #pragma unroll
    for (int i = 0; i < 30; ++i) w[i] = vbb[oy][xs + i];
    #pragma unroll
    for (int j = 0; j < 16; ++j) {
        float a = 0.f;
        #pragma unroll
        for (int d = 0; d < KS; ++d) a += k10s[d] * w[j + d];
        res[j] = a;
    }
    if (norm_mode) {
        #pragma unroll
        for (int j = 0; j < 16; ++j) outb[rowp + j] = 1.0f / res[j];
    } else {
        #pragma unroll
        for (int j = 0; j < 16; ++j) outb[ob + j] = res[j] * rbn[rowp + j];
    }
}

// ---------------------------------------------------------------------------
// q_{i+1} = u - (M1@spo + M2@blo) - cru(q_i); then (unless last) softmax and
// clique reduction for iteration i+1, fused.
// ---------------------------------------------------------------------------
__global__ void __launch_bounds__(256, 1)
k_update(const float* __restrict__ un,
         const float* __restrict__ spo,
         const float* __restrict__ blo,
         const float* __restrict__ M1t,   // [k][c]
         const float* __restrict__ M2t,
         const float* __restrict__ d1,
         const float* __restrict__ d2,
         const int* __restrict__ dflag,
         const float* __restrict__ sums_cur,
         float* __restrict__ sums_next,
         const float* __restrict__ lwg,
         const float* __restrict__ hwg,
         const int* __restrict__ spmT,
         const int* __restrict__ spidx, int iter,
         float* __restrict__ q,
         float* __restrict__ sm,
         float* __restrict__ out, int last) {
    __shared__ float lun[256*CC];
    __shared__ float slse[3*CC];
    {
        const float4* src = (const float4*)(un + (size_t)blockIdx.x*(256*CC));
        float4* dst = (float4*)lun;
        for (int i = threadIdx.x; i < (256*CC)/4; i += 256) dst[i] = src[i];
    }
    if (threadIdx.x < 3*CC) {
        float s = 0.f;
        #pragma unroll
        for (int b = 0; b < NBKT; ++b) s += sums_cur[b*64 + threadIdx.x];
        slse[threadIdx.x] = FLOG((float)HWN + s);
    }
    __syncthreads();

    int p = blockIdx.x * blockDim.x + threadIdx.x;
    int sidx = spidx[iter];
    int s = spmT[p];
    float f1 = (s == sidx)     ? 1.f : 0.f;
    float f2 = (s == sidx + 1) ? 1.f : 0.f;

    float acc[CC];
    if (dflag[0]) {
        #pragma unroll
        for (int c = 0; c < CC; ++c)
            acc[c] = d1[c] * spo[c*HWN + p] + d2[c] * blo[c*HWN + p];
    } else {
        #pragma unroll
        for (int c = 0; c < CC; ++c) acc[c] = 0.f;
        #pragma unroll
        for (int k = 0; k < CC; ++k) {
            float sv = spo[k*HWN + p];
            float bv = blo[k*HWN + p];
            #pragma unroll
            for (int c = 0; c < CC; ++c)
                acc[c] += M1t[k*CC + c] * sv + M2t[k*CC + c] * bv;
        }
    }

    float v[CC];
    #pragma unroll
    for (int c = 0; c < CC; ++c) v[c] = q[c*HWN + p];
    float mx = v[0];
    #pragma unroll
    for (int c = 1; c < CC; ++c) mx = fmaxf(mx, v[c]);

    float hw0 = hwg[0], hw1 = hwg[1], hw2 = hwg[2];
    int tb = threadIdx.x * CC;
    #pragma unroll
    for (int c = 0; c < CC; ++c) {
        float qv = v[c];
        float qmod = qv + ((qv == 0.f) ? 1.f : 0.f);
        float anp = f1 * (qv + mx) - ((f1 != 0.f && qv == mx) ? qv : 0.f);
        float qst = anp + ((anp == 0.f) ? 1.f : 0.f);
        float p1 = f1 * slse[c];
        float p2 = f1 * slse[CC + c];
        float p3 = p1 + f2 * slse[2*CC + c];
        float rq = FRCP(qmod);
        float rs = FRCP(qst);
        float ft1 = p1 * rq;
        float ft2 = p2 * rs;
        float ft3 = p3 * rq;
        float cru = lwg[c]*ft1        + hw0*(1.f - ft1)
                  + lwg[CC + c]*ft2   + hw1*(1.f - ft2)
                  + lwg[2*CC + c]*ft3 + hw2*(1.f - ft3);
        float qn = lun[tb + c] - acc[c] - cru;
        q[c*HWN + p] = qn;
        acc[c] = qn;
        if (last) lun[tb + c] = qn;
    }

    if (!last) {
        float mx2 = acc[0];
        #pragma unroll
        for (int c = 1; c < CC; ++c) mx2 = fmaxf(mx2, acc[c]);
        float e[CC], ssum = 0.f;
        #pragma unroll
        for (int c = 0; c < CC; ++c) { e[c] = FEXP(acc[c] - mx2); ssum += e[c]; }
        float inv = FRCP(ssum);
        #pragma unroll
        for (int c = 0; c < CC; ++c) sm[c*HWN + p] = e[c] * inv;

        int sidx2 = spidx[iter + 1];
        bool c1 = (s == sidx2), c2 = (s == sidx2 + 1);
        if (c1 || c2) {
            float* bkt = sums_next + (blockIdx.x & (NBKT-1)) * 64;
            float emx = FEXP(mx2);
            if (c1) {
                #pragma unroll
                for (int c = 0; c < CC; ++c) {
                    float ev = e[c] * emx;
                    atomicAdd(&bkt[c], ev - 1.0f);
                    float ea = (acc[c] == mx2) ? emx : ev * emx;
                    atomicAdd(&bkt[CC + c], ea - 1.0f);
                }
            } else {
                #pragma unroll
                for (int c = 0; c < CC; ++c) atomicAdd(&bkt[2*CC + c], e[c] * emx - 1.0f);
            }
        }
    } else {
        __syncthreads();
        float4* dst = (float4*)(out + (size_t)blockIdx.x*(256*CC));
        const float4* src = (const float4*)lun;
        for (int i = threadIdx.x; i < (256*CC)/4; i += 256) dst[i] = src[i];
    }
}

// ---------------------------------------------------------------------------
extern "C" void kernel_launch(void* const* d_in, const int* in_sizes, int n_in,
                              void* d_out, int out_size, void* d_ws, size_t ws_size,
                              hipStream_t stream) {
    const float* un    = (const float*)d_in[0];
    const float* rgb   = (const float*)d_in[1];
    const int*   spin  = (const int*)  d_in[2];
    const int*   spidx = (const int*)  d_in[3];
    const float* skw   = (const float*)d_in[4];
    const float* bkw   = (const float*)d_in[5];
    const float* lw    = (const float*)d_in[6];
    const float* hwv   = (const float*)d_in[7];
    const float* cm    = (const float*)d_in[8];
    float* out = (float*)d_out;

    float* ws = (float*)d_ws;
    float* q     = ws;
    float* sm    = ws + (size_t)CHW;
    float* a     = ws + (size_t)2*CHW;     // spatial_out
    float* b     = ws + (size_t)3*CHW;     // bilateral_out
    float* guide = ws + (size_t)4*CHW;
    float* rsn   = guide + HWN;            // reciprocal spatial norm
    float* rbn   = rsn + HWN;
    int*   spmT  = (int*)(rbn + HWN);
    float* M1t   = rbn + 2*(size_t)HWN;    // after spmT (HWN ints)
    float* M2t   = M1t + CC*CC;
    float* d1    = M2t + CC*CC;
    float* d2    = d1 + CC;
    int*   dflag = (int*)(d2 + CC);
    float* kbuf  = d2 + CC + 4;
    float* sums  = kbuf + 2*KS;            // NITER * NBKT * 64 floats

    dim3 blk(256);
    int gpix = HWN / 256;                  // 1024 blocks
    dim3 gblur(WW/TW, HH/TH, CC);          // 4 x 16 x 21
    dim3 gnorm(WW/TW, HH/TH, 1);

    k_init_small<<<1, 512, 0, stream>>>(cm, skw, bkw, M1t, M2t, d1, d2, dflag,
                                        kbuf, sums);
    k_init_maps<<<gpix, blk, 0, stream>>>(rgb, spin, un, guide, spmT, q, sm,
                                          spidx, sums);
    k_blur<<<gnorm, blk, 0, stream>>>(nullptr, guide, rsn, rbn,
                                      nullptr, nullptr, kbuf, 1);

    for (int it = 0; it < NITER; ++it) {
        int last = (it == NITER - 1) ? 1 : 0;
        float* su  = sums + it*NBKT*64;
        float* sun = last ? nullptr : (sums + (it+1)*NBKT*64);
        k_blur<<<gblur, blk, 0, stream>>>(sm, guide, a, b, rsn, rbn, kbuf, 0);
        k_update<<<gpix, blk, 0, stream>>>(un, a, b, M1t, M2t, d1, d2, dflag,
                                           su, sun, lw, hwv,
                                           spmT, spidx, it, q, sm, out, last);
    }
}

// Round 5
// 446.303 us; speedup vs baseline: 8.0034x; 1.2276x over previous
//
#include <hip/hip_runtime.h>
#include <math.h>

#define CC 21
#define HH 512
#define WW 512
#define HWN (HH*WW)
#define CHW (CC*HWN)
#define RAD 7
#define KS 15
#define NITER 5
#define NBKT 16

#define TW 128
#define TH 32
#define TWH (TW + 2*RAD)   // 142
#define LSTR 145           // ODD LDS row stride -> spreads h-pass banks

#define FEXP(x) __expf(x)
#define FLOG(x) __logf(x)
#define FRCP(x) __builtin_amdgcn_rcpf(x)

// ---------------------------------------------------------------------------
// init: M1t[k][c] = (CM@SKW)[c][k], M2t[k][c] = (CM@BKW)[c][k], taps, zero
// sums, diagonality flag + diagonal extracts (all parallel, no serial loop)
// ---------------------------------------------------------------------------
__global__ void k_init_small(const float* __restrict__ cm,
                             const float* __restrict__ skw,
                             const float* __restrict__ bkw,
                             float* __restrict__ M1t, float* __restrict__ M2t,
                             float* __restrict__ d1, float* __restrict__ d2,
                             int* __restrict__ dflag,
                             float* __restrict__ kbuf,
                             float* __restrict__ sums) {
    __shared__ int sbad;
    int t = threadIdx.x;
    if (t == 0) sbad = 0;
    __syncthreads();
    if (t < CC*CC) {
        int k = t / CC, c = t % CC;
        float a = 0.f, b = 0.f;
        for (int m = 0; m < CC; ++m) {
            a += cm[c*CC+m] * skw[m*CC+k];
            b += cm[c*CC+m] * bkw[m*CC+k];
        }
        M1t[t] = a; M2t[t] = b;
        if (k != c && (a != 0.f || b != 0.f)) atomicOr(&sbad, 1);
        if (k == c) { d1[c] = a; d2[c] = b; }
    }
    for (int i = t; i < NITER*NBKT*64; i += blockDim.x) sums[i] = 0.f;
    if (t == CC*CC) {
        float w3[KS], w10[KS];
        float s3 = 0.f, s10 = 0.f;
        for (int i = 0; i < KS; ++i) {
            float x = (float)(i - RAD);
            w3[i]  = expf(-0.5f * (x/3.0f)  * (x/3.0f));
            w10[i] = expf(-0.5f * (x/10.0f) * (x/10.0f));
            s3 += w3[i]; s10 += w10[i];
        }
        for (int i = 0; i < KS; ++i) {
            kbuf[i]      = w3[i]  / s3;
            kbuf[KS + i] = w10[i] / s10;
        }
    }
    __syncthreads();
    if (t == 0) dflag[0] = sbad ? 0 : 1;
}

// ---------------------------------------------------------------------------
// guide, spmT, sm0 = softmax(un), clique sums for iter 0.  (q0 == un, no copy)
// ---------------------------------------------------------------------------
__global__ void k_init_maps(const float* __restrict__ rgb,
                            const int* __restrict__ spin,
                            const float* __restrict__ un,
                            float* __restrict__ guide,
                            int* __restrict__ spmT,
                            float* __restrict__ sm,
                            const int* __restrict__ spidx,
                            float* __restrict__ sums0) {
    int p = blockIdx.x * blockDim.x + threadIdx.x;
    int h = p / WW, w = p - h*WW;
    float r = rgb[p*3+0] * (1.0f/255.0f);
    float g = rgb[p*3+1] * (1.0f/255.0f);
    float b = rgb[p*3+2] * (1.0f/255.0f);
    guide[p] = FEXP(-0.5f * (r*r + g*g + b*b) / 9.0f);   // theta_beta^2 = 9
    int s = spin[w*HH + h];
    spmT[p] = s;
    float v[CC];
    #pragma unroll
    for (int c = 0; c < CC; ++c) v[c] = un[p*CC + c];
    float mx = v[0];
    #pragma unroll
    for (int c = 1; c < CC; ++c) mx = fmaxf(mx, v[c]);
    float e[CC], ssum = 0.f;
    #pragma unroll
    for (int c = 0; c < CC; ++c) { e[c] = FEXP(v[c] - mx); ssum += e[c]; }
    float inv = FRCP(ssum);
    #pragma unroll
    for (int c = 0; c < CC; ++c) sm[c*HWN + p] = e[c] * inv;

    int sidx = spidx[0];
    bool c1 = (s == sidx), c2 = (s == sidx + 1);
    if (c1 || c2) {
        float* bkt = sums0 + (blockIdx.x & (NBKT-1)) * 64;
        float emx = FEXP(mx);
        if (c1) {
            #pragma unroll
            for (int c = 0; c < CC; ++c) {
                float ev = e[c] * emx;                       // exp(q)
                atomicAdd(&bkt[c], ev - 1.0f);
                float ea = (v[c] == mx) ? emx : ev * emx;    // exp(A_np)
                atomicAdd(&bkt[CC + c], ea - 1.0f);
            }
        } else {
            #pragma unroll
            for (int c = 0; c < CC; ++c) atomicAdd(&bkt[2*CC + c], e[c] * emx - 1.0f);
        }
    }
}

// ---------------------------------------------------------------------------
// fused separable blur (spatial sigma=3 AND bilateral sigma=10 w/ guide premul)
// tile 128x32, v-pass in registers, h-pass from LDS (odd stride).
// ---------------------------------------------------------------------------
__global__ void __launch_bounds__(256, 3)
k_blur(const float* __restrict__ in,       // null in norm mode
       const float* __restrict__ guide,
       float* __restrict__ outs, float* __restrict__ outb,
       const float* __restrict__ rsn, const float* __restrict__ rbn,
       const float* __restrict__ kbuf, int norm_mode) {
    __shared__ float vbs[TH][LSTR];
    __shared__ float vbb[TH][LSTR];
    __shared__ float k3s[KS], k10s[KS];
    int t = threadIdx.x;
    if (t < KS) { k3s[t] = kbuf[t]; k10s[t] = kbuf[KS + t]; }
    __syncthreads();

    int c  = blockIdx.z;
    int x0 = blockIdx.x * TW;
    int y0 = blockIdx.y * TH;
    const float* base = in ? (in + (size_t)c*HWN) : nullptr;

    if (t < TWH) {
        int xg = x0 - RAD + t;
        bool xok = (xg >= 0 && xg < WW);
        float ws_[KS], wb_[KS];
        #pragma unroll
        for (int i = 0; i < KS-1; ++i) {
            int yg = y0 - RAD + i;
            bool ok = xok && (yg >= 0) && (yg < HH);
            float v = 0.f, g = 0.f;
            if (ok) { g = guide[yg*WW + xg]; v = base ? base[yg*WW + xg] : 1.0f; }
            ws_[i] = v; wb_[i] = v * g;
        }
        #pragma unroll
        for (int y = 0; y < TH; ++y) {
            int yg = y0 + y + RAD;
            bool ok = xok && (yg < HH);
            float v = 0.f, g = 0.f;
            if (ok) { g = guide[yg*WW + xg]; v = base ? base[yg*WW + xg] : 1.0f; }
            ws_[(KS-1+y)%KS] = v; wb_[(KS-1+y)%KS] = v * g;
            float as = 0.f, ab = 0.f;
            #pragma unroll
            for (int d = 0; d < KS; ++d) {
                as += k3s[d]  * ws_[(y+d)%KS];
                ab += k10s[d] * wb_[(y+d)%KS];
            }
            vbs[y][t] = as; vbb[y][t] = ab;
        }
    }
    __syncthreads();

    // h-pass: 256 threads = 32 rows x 8 groups of 16 consecutive outputs
    int oy = t >> 3;
    int xs = (t & 7) * 16;
    int gy = y0 + oy;
    int rowp  = gy*WW + x0 + xs;
    size_t ob = (size_t)c*HWN + rowp;

    float w[30], res[16];
    #pragma unroll
    for (int i = 0; i < 30; ++i) w[i] = vbs[oy][xs + i];
    #pragma unroll
    for (int j = 0; j < 16; ++j) {
        float a = 0.f;
        #pragma unroll
        for (int d = 0; d < KS; ++d) a += k3s[d] * w[j + d];
        res[j] = a;
    }
    if (norm_mode) {
        #pragma unroll
        for (int j = 0; j < 16; ++j) outs[rowp + j] = 1.0f / res[j];
    } else {
        #pragma unroll
        for (int j = 0; j < 16; ++j) outs[ob + j] = res[j] * rsn[rowp + j];
    }

    #pragma unroll
    for (int i = 0; i < 30; ++i) w[i] = vbb[oy][xs + i];
    #pragma unroll
    for (int j = 0; j < 16; ++j) {
        float a = 0.f;
        #pragma unroll
        for (int d = 0; d < KS; ++d) a += k10s[d] * w[j + d];
        res[j] = a;
    }
    if (norm_mode) {
        #pragma unroll
        for (int j = 0; j < 16; ++j) outb[rowp + j] = 1.0f / res[j];
    } else {
        #pragma unroll
        for (int j = 0; j < 16; ++j) outb[ob + j] = res[j] * rbn[rowp + j];
    }
}

// ---------------------------------------------------------------------------
// q_{i+1} = u - (M1@spo + M2@blo) - cru(q_i); then (unless last) softmax and
// clique reduction for iteration i+1, fused.  q/un/out are pixel-major.
// ---------------------------------------------------------------------------
__global__ void __launch_bounds__(256, 2)
k_update(const float* __restrict__ un,
         const float* __restrict__ qin,   // == un on iter 0, else q
         const float* __restrict__ spo,
         const float* __restrict__ blo,
         const float* __restrict__ M1t,   // [k][c]
         const float* __restrict__ M2t,
         const float* __restrict__ d1,
         const float* __restrict__ d2,
         const int* __restrict__ dflag,
         const float* __restrict__ sums_cur,
         float* __restrict__ sums_next,
         const float* __restrict__ lwg,
         const float* __restrict__ hwg,
         const int* __restrict__ spmT,
         const int* __restrict__ spidx, int iter,
         float* __restrict__ q,
         float* __restrict__ sm,
         float* __restrict__ out, int last) {
    __shared__ float slse[3*CC];
    if (threadIdx.x < 3*CC) {
        float s = 0.f;
        #pragma unroll
        for (int b = 0; b < NBKT; ++b) s += sums_cur[b*64 + threadIdx.x];
        slse[threadIdx.x] = FLOG((float)HWN + s);
    }
    __syncthreads();

    int p = blockIdx.x * blockDim.x + threadIdx.x;
    int sidx = spidx[iter];
    int s = spmT[p];
    float f1 = (s == sidx)     ? 1.f : 0.f;
    float f2 = (s == sidx + 1) ? 1.f : 0.f;

    float acc[CC];
    if (dflag[0]) {
        #pragma unroll
        for (int c = 0; c < CC; ++c)
            acc[c] = d1[c] * spo[c*HWN + p] + d2[c] * blo[c*HWN + p];
    } else {
        #pragma unroll
        for (int c = 0; c < CC; ++c) acc[c] = 0.f;
        #pragma unroll
        for (int k = 0; k < CC; ++k) {
            float sv = spo[k*HWN + p];
            float bv = blo[k*HWN + p];
            #pragma unroll
            for (int c = 0; c < CC; ++c)
                acc[c] += M1t[k*CC + c] * sv + M2t[k*CC + c] * bv;
        }
    }

    float v[CC];
    #pragma unroll
    for (int c = 0; c < CC; ++c) v[c] = qin[p*CC + c];

    float hw0 = hwg[0], hw1 = hwg[1], hw2 = hwg[2];
    bool any_clique = __any(f1 != 0.f || f2 != 0.f);
    if (any_clique) {
        float mx = v[0];
        #pragma unroll
        for (int c = 1; c < CC; ++c) mx = fmaxf(mx, v[c]);
        #pragma unroll
        for (int c = 0; c < CC; ++c) {
            float qv = v[c];
            float qmod = qv + ((qv == 0.f) ? 1.f : 0.f);
            float anp = f1 * (qv + mx) - ((f1 != 0.f && qv == mx) ? qv : 0.f);
            float qst = anp + ((anp == 0.f) ? 1.f : 0.f);
            float p1 = f1 * slse[c];
            float p2 = f1 * slse[CC + c];
            float p3 = p1 + f2 * slse[2*CC + c];
            float ft1 = p1 * FRCP(qmod);
            float ft2 = p2 * FRCP(qst);
            float ft3 = p3 * FRCP(qmod);
            float cru = lwg[c]*ft1        + hw0*(1.f - ft1)
                      + lwg[CC + c]*ft2   + hw1*(1.f - ft2)
                      + lwg[2*CC + c]*ft3 + hw2*(1.f - ft3);
            acc[c] = un[p*CC + c] - acc[c] - cru;
        }
    } else {
        float cruc = hw0 + hw1 + hw2;   // all ft == 0
        #pragma unroll
        for (int c = 0; c < CC; ++c)
            acc[c] = un[p*CC + c] - acc[c] - cruc;
    }

    if (!last) {
        #pragma unroll
        for (int c = 0; c < CC; ++c) q[p*CC + c] = acc[c];
        float mx2 = acc[0];
        #pragma unroll
        for (int c = 1; c < CC; ++c) mx2 = fmaxf(mx2, acc[c]);
        float e[CC], ssum = 0.f;
        #pragma unroll
        for (int c = 0; c < CC; ++c) { e[c] = FEXP(acc[c] - mx2); ssum += e[c]; }
        float inv = FRCP(ssum);
        #pragma unroll
        for (int c = 0; c < CC; ++c) sm[c*HWN + p] = e[c] * inv;

        int sidx2 = spidx[iter + 1];
        bool c1 = (s == sidx2), c2 = (s == sidx2 + 1);
        if (c1 || c2) {
            float* bkt = sums_next + (blockIdx.x & (NBKT-1)) * 64;
            float emx = FEXP(mx2);
            if (c1) {
                #pragma unroll
                for (int c = 0; c < CC; ++c) {
                    float ev = e[c] * emx;
                    atomicAdd(&bkt[c], ev - 1.0f);
                    float ea = (acc[c] == mx2) ? emx : ev * emx;
                    atomicAdd(&bkt[CC + c], ea - 1.0f);
                }
            } else {
                #pragma unroll
                for (int c = 0; c < CC; ++c) atomicAdd(&bkt[2*CC + c], e[c] * emx - 1.0f);
            }
        }
    } else {
        #pragma unroll
        for (int c = 0; c < CC; ++c) out[p*CC + c] = acc[c];
    }
}

// ---------------------------------------------------------------------------
extern "C" void kernel_launch(void* const* d_in, const int* in_sizes, int n_in,
                              void* d_out, int out_size, void* d_ws, size_t ws_size,
                              hipStream_t stream) {
    const float* un    = (const float*)d_in[0];
    const float* rgb   = (const float*)d_in[1];
    const int*   spin  = (const int*)  d_in[2];
    const int*   spidx = (const int*)  d_in[3];
    const float* skw   = (const float*)d_in[4];
    const float* bkw   = (const float*)d_in[5];
    const float* lw    = (const float*)d_in[6];
    const float* hwv   = (const float*)d_in[7];
    const float* cm    = (const float*)d_in[8];
    float* out = (float*)d_out;

    float* ws = (float*)d_ws;
    float* q     = ws;                     // pixel-major (p, c)
    float* sm    = ws + (size_t)CHW;       // channel-planar (c, p)
    float* a     = ws + (size_t)2*CHW;     // spatial_out (planar)
    float* b     = ws + (size_t)3*CHW;     // bilateral_out (planar)
    float* guide = ws + (size_t)4*CHW;
    float* rsn   = guide + HWN;            // reciprocal spatial norm
    float* rbn   = rsn + HWN;
    int*   spmT  = (int*)(rbn + HWN);
    float* M1t   = rbn + 2*(size_t)HWN;    // after spmT (HWN ints)
    float* M2t   = M1t + CC*CC;
    float* d1    = M2t + CC*CC;
    float* d2    = d1 + CC;
    int*   dflag = (int*)(d2 + CC);
    float* kbuf  = d2 + CC + 4;
    float* sums  = kbuf + 2*KS;            // NITER * NBKT * 64 floats

    dim3 blk(256);
    int gpix = HWN / 256;                  // 1024 blocks
    dim3 gblur(WW/TW, HH/TH, CC);          // 4 x 16 x 21
    dim3 gnorm(WW/TW, HH/TH, 1);

    k_init_small<<<1, 512, 0, stream>>>(cm, skw, bkw, M1t, M2t, d1, d2, dflag,
                                        kbuf, sums);
    k_init_maps<<<gpix, blk, 0, stream>>>(rgb, spin, un, guide, spmT, sm,
                                          spidx, sums);
    k_blur<<<gnorm, blk, 0, stream>>>(nullptr, guide, rsn, rbn,
                                      nullptr, nullptr, kbuf, 1);

    for (int it = 0; it < NITER; ++it) {
        int last = (it == NITER - 1) ? 1 : 0;
        float* su  = sums + it*NBKT*64;
        float* sun = last ? nullptr : (sums + (it+1)*NBKT*64);
        const float* qin = (it == 0) ? un : q;
        k_blur<<<gblur, blk, 0, stream>>>(sm, guide, a, b, rsn, rbn, kbuf, 0);
        k_update<<<gpix, blk, 0, stream>>>(un, qin, a, b, M1t, M2t, d1, d2, dflag,
                                           su, sun, lw, hwv,
                                           spmT, spidx, it, q, sm, out, last);
    }
}

// Round 6
// 343.096 us; speedup vs baseline: 10.4110x; 1.3008x over previous
//
#include <hip/hip_runtime.h>
#include <math.h>

#define CC 21
#define HH 512
#define WW 512
#define HWN (HH*WW)
#define CHW (CC*HWN)
#define RAD 7
#define KS 15
#define NITER 5
#define NBKT 16

#define TW 128
#define TH 16
#define TWH (TW + 2*RAD)   // 142
#define LSTR 145           // odd LDS row stride

#define FEXP(x) __expf(x)
#define FLOG(x) __logf(x)
#define FRCP(x) __builtin_amdgcn_rcpf(x)

// ---------------------------------------------------------------------------
// init: M1t/M2t, diag extracts + flag, taps, zero sums (all parallel)
// ---------------------------------------------------------------------------
__global__ void k_init_small(const float* __restrict__ cm,
                             const float* __restrict__ skw,
                             const float* __restrict__ bkw,
                             float* __restrict__ M1t, float* __restrict__ M2t,
                             float* __restrict__ d1, float* __restrict__ d2,
                             int* __restrict__ dflag,
                             float* __restrict__ kbuf,
                             float* __restrict__ sums) {
    __shared__ int sbad;
    int t = threadIdx.x;
    if (t == 0) sbad = 0;
    __syncthreads();
    if (t < CC*CC) {
        int k = t / CC, c = t % CC;
        float a = 0.f, b = 0.f;
        for (int m = 0; m < CC; ++m) {
            a += cm[c*CC+m] * skw[m*CC+k];
            b += cm[c*CC+m] * bkw[m*CC+k];
        }
        M1t[t] = a; M2t[t] = b;
        if (k != c && (a != 0.f || b != 0.f)) atomicOr(&sbad, 1);
        if (k == c) { d1[c] = a; d2[c] = b; }
    }
    for (int i = t; i < NITER*NBKT*64; i += blockDim.x) sums[i] = 0.f;
    if (t == CC*CC) {
        float w3[KS], w10[KS];
        float s3 = 0.f, s10 = 0.f;
        for (int i = 0; i < KS; ++i) {
            float x = (float)(i - RAD);
            w3[i]  = expf(-0.5f * (x/3.0f)  * (x/3.0f));
            w10[i] = expf(-0.5f * (x/10.0f) * (x/10.0f));
            s3 += w3[i]; s10 += w10[i];
        }
        for (int i = 0; i < KS; ++i) {
            kbuf[i]      = w3[i]  / s3;
            kbuf[KS + i] = w10[i] / s10;
        }
    }
    __syncthreads();
    if (t == 0) dflag[0] = sbad ? 0 : 1;
}

// ---------------------------------------------------------------------------
// guide, spmT, sm0 = softmax(un), clique sums for iter 0.  (q0 == un)
// ---------------------------------------------------------------------------
__global__ void k_init_maps(const float* __restrict__ rgb,
                            const int* __restrict__ spin,
                            const float* __restrict__ un,
                            float* __restrict__ guide,
                            int* __restrict__ spmT,
                            float* __restrict__ sm,
                            const int* __restrict__ spidx,
                            float* __restrict__ sums0) {
    int p = blockIdx.x * blockDim.x + threadIdx.x;
    int h = p / WW, w = p - h*WW;
    float r = rgb[p*3+0] * (1.0f/255.0f);
    float g = rgb[p*3+1] * (1.0f/255.0f);
    float b = rgb[p*3+2] * (1.0f/255.0f);
    guide[p] = FEXP(-0.5f * (r*r + g*g + b*b) / 9.0f);   // theta_beta^2 = 9
    int s = spin[w*HH + h];
    spmT[p] = s;
    float v[CC];
    #pragma unroll
    for (int c = 0; c < CC; ++c) v[c] = un[p*CC + c];
    float mx = v[0];
    #pragma unroll
    for (int c = 1; c < CC; ++c) mx = fmaxf(mx, v[c]);
    float e[CC], ssum = 0.f;
    #pragma unroll
    for (int c = 0; c < CC; ++c) { e[c] = FEXP(v[c] - mx); ssum += e[c]; }
    float inv = FRCP(ssum);
    #pragma unroll
    for (int c = 0; c < CC; ++c) sm[c*HWN + p] = e[c] * inv;

    int sidx = spidx[0];
    bool c1 = (s == sidx), c2 = (s == sidx + 1);
    if (c1 || c2) {
        float* bkt = sums0 + (blockIdx.x & (NBKT-1)) * 64;
        float emx = FEXP(mx);
        if (c1) {
            #pragma unroll
            for (int c = 0; c < CC; ++c) {
                float ev = e[c] * emx;                       // exp(q)
                atomicAdd(&bkt[c], ev - 1.0f);
                float ea = (v[c] == mx) ? emx : ev * emx;    // exp(A_np)
                atomicAdd(&bkt[CC + c], ea - 1.0f);
            }
        } else {
            #pragma unroll
            for (int c = 0; c < CC; ++c) atomicAdd(&bkt[2*CC + c], e[c] * emx - 1.0f);
        }
    }
}

// ---------------------------------------------------------------------------
// fused separable blur. tile 128x16. v-pass: 284 units (142 cols x 2 row
// halves) over all 256 threads. h-pass: oy=t&15, xs=(t>>4)*8 (2-way banks).
// mode: norm_mode -> write reciprocal norms; else if diag -> write combined
// pairwise plane into outs; else write both normalized planes.
// ---------------------------------------------------------------------------
__global__ void __launch_bounds__(256, 4)
k_blur(const float* __restrict__ in,       // null in norm mode
       const float* __restrict__ guide,
       float* __restrict__ outs, float* __restrict__ outb,
       const float* __restrict__ rsn, const float* __restrict__ rbn,
       const float* __restrict__ d1, const float* __restrict__ d2,
       const int* __restrict__ dflag,
       const float* __restrict__ kbuf, int norm_mode) {
    __shared__ float vbs[TH][LSTR];
    __shared__ float vbb[TH][LSTR];
    __shared__ float k3s[KS], k10s[KS];
    int t = threadIdx.x;
    if (t < KS) { k3s[t] = kbuf[t]; k10s[t] = kbuf[KS + t]; }
    __syncthreads();

    int c  = blockIdx.z;
    int x0 = blockIdx.x * TW;
    int y0 = blockIdx.y * TH;
    const float* base = in ? (in + (size_t)c*HWN) : nullptr;

    // ---- v-pass: all threads; unit = (col, 8-row half) ----
    for (int u = t; u < 2*TWH; u += 256) {
        int col  = (u < TWH) ? u : u - TWH;
        int half = (u < TWH) ? 0 : 1;
        int xg = x0 - RAD + col;
        bool xok = (xg >= 0 && xg < WW);
        int yb = y0 + half*8;                 // first output row (global)
        float ws_[KS], wb_[KS];
        #pragma unroll
        for (int i = 0; i < KS-1; ++i) {      // preload rows yb-7 .. yb+6
            int yg = yb - RAD + i;
            bool ok = xok && (yg >= 0) && (yg < HH);
            float v = 0.f, g = 0.f;
            if (ok) { g = guide[yg*WW + xg]; v = base ? base[yg*WW + xg] : 1.0f; }
            ws_[i] = v; wb_[i] = v * g;
        }
        #pragma unroll
        for (int y = 0; y < 8; ++y) {
            int yg = yb + y + RAD;
            bool ok = xok && (yg < HH);
            float v = 0.f, g = 0.f;
            if (ok) { g = guide[yg*WW + xg]; v = base ? base[yg*WW + xg] : 1.0f; }
            ws_[(KS-1+y)%KS] = v; wb_[(KS-1+y)%KS] = v * g;
            float as = 0.f, ab = 0.f;
            #pragma unroll
            for (int d = 0; d < KS; ++d) {
                as += k3s[d]  * ws_[(y+d)%KS];
                ab += k10s[d] * wb_[(y+d)%KS];
            }
            vbs[half*8 + y][col] = as; vbb[half*8 + y][col] = ab;
        }
    }
    __syncthreads();

    // ---- h-pass: 8 outputs per thread ----
    int oy = t & 15;
    int xs = (t >> 4) * 8;
    int gy = y0 + oy;
    int rowp = gy*WW + x0 + xs;
    size_t ob = (size_t)c*HWN + rowp;

    float wS[22], wB[22];
    #pragma unroll
    for (int i = 0; i < 22; ++i) { wS[i] = vbs[oy][xs + i]; wB[i] = vbb[oy][xs + i]; }

    float resS[8], resB[8];
    #pragma unroll
    for (int j = 0; j < 8; ++j) {
        float a = 0.f, b = 0.f;
        #pragma unroll
        for (int d = 0; d < KS; ++d) { a += k3s[d] * wS[j + d]; b += k10s[d] * wB[j + d]; }
        resS[j] = a; resB[j] = b;
    }

    if (norm_mode) {
        #pragma unroll
        for (int j = 0; j < 8; ++j) {
            outs[rowp + j] = 1.0f / resS[j];
            outb[rowp + j] = 1.0f / resB[j];
        }
    } else if (dflag[0]) {
        float d1c = d1[c], d2c = d2[c];
        #pragma unroll
        for (int j = 0; j < 8; ++j)
            outs[ob + j] = d1c * resS[j] * rsn[rowp + j]
                         + d2c * resB[j] * rbn[rowp + j];
    } else {
        #pragma unroll
        for (int j = 0; j < 8; ++j) {
            outs[ob + j] = resS[j] * rsn[rowp + j];
            outb[ob + j] = resB[j] * rbn[rowp + j];
        }
    }
}

// ---------------------------------------------------------------------------
// q_{i+1} = u - pairwise - cru(q_i); then (unless last) softmax + clique
// reduction for iter i+1.  q is read/written ONLY at clique pixels.
// diag mode: pw = combined pairwise plane; dense: pw=spatial, blo=bilateral.
// ---------------------------------------------------------------------------
__global__ void __launch_bounds__(256, 4)
k_update(const float* __restrict__ un,
         const float* __restrict__ qin,   // == un on iter 0, else q (sparse-valid)
         const float* __restrict__ pw,
         const float* __restrict__ blo,
         const float* __restrict__ M1t,   // [k][c]
         const float* __restrict__ M2t,
         const int* __restrict__ dflag,
         const float* __restrict__ sums_cur,
         float* __restrict__ sums_next,
         const float* __restrict__ lwg,
         const float* __restrict__ hwg,
         const int* __restrict__ spmT,
         const int* __restrict__ spidx, int iter,
         float* __restrict__ q,
         float* __restrict__ sm,
         float* __restrict__ out, int last) {
    __shared__ float slse[3*CC];
    if (threadIdx.x < 3*CC) {
        float s = 0.f;
        #pragma unroll
        for (int b = 0; b < NBKT; ++b) s += sums_cur[b*64 + threadIdx.x];
        slse[threadIdx.x] = FLOG((float)HWN + s);
    }
    __syncthreads();

    int p = blockIdx.x * blockDim.x + threadIdx.x;
    int sidx = spidx[iter];
    int s = spmT[p];
    float f1 = (s == sidx)     ? 1.f : 0.f;
    float f2 = (s == sidx + 1) ? 1.f : 0.f;

    float acc[CC];
    if (dflag[0]) {
        #pragma unroll
        for (int c = 0; c < CC; ++c) acc[c] = pw[c*HWN + p];
    } else {
        #pragma unroll
        for (int c = 0; c < CC; ++c) acc[c] = 0.f;
        #pragma unroll
        for (int k = 0; k < CC; ++k) {
            float sv = pw[k*HWN + p];
            float bv = blo[k*HWN + p];
            #pragma unroll
            for (int c = 0; c < CC; ++c)
                acc[c] += M1t[k*CC + c] * sv + M2t[k*CC + c] * bv;
        }
    }

    float hw0 = hwg[0], hw1 = hwg[1], hw2 = hwg[2];
    bool any_clique = __any(f1 != 0.f || f2 != 0.f);
    if (any_clique) {
        float v[CC];
        #pragma unroll
        for (int c = 0; c < CC; ++c) v[c] = qin[p*CC + c];
        float mx = v[0];
        #pragma unroll
        for (int c = 1; c < CC; ++c) mx = fmaxf(mx, v[c]);
        #pragma unroll
        for (int c = 0; c < CC; ++c) {
            float qv = v[c];
            float qmod = qv + ((qv == 0.f) ? 1.f : 0.f);
            float anp = f1 * (qv + mx) - ((f1 != 0.f && qv == mx) ? qv : 0.f);
            float qst = anp + ((anp == 0.f) ? 1.f : 0.f);
            float p1 = f1 * slse[c];
            float p2 = f1 * slse[CC + c];
            float p3 = p1 + f2 * slse[2*CC + c];
            float ft1 = p1 * FRCP(qmod);
            float ft2 = p2 * FRCP(qst);
            float ft3 = p3 * FRCP(qmod);
            float cru = lwg[c]*ft1        + hw0*(1.f - ft1)
                      + lwg[CC + c]*ft2   + hw1*(1.f - ft2)
                      + lwg[2*CC + c]*ft3 + hw2*(1.f - ft3);
            acc[c] = un[p*CC + c] - acc[c] - cru;
        }
    } else {
        float cruc = hw0 + hw1 + hw2;   // all ft == 0
        #pragma unroll
        for (int c = 0; c < CC; ++c)
            acc[c] = un[p*CC + c] - acc[c] - cruc;
    }

    if (!last) {
        int sidx2 = spidx[iter + 1];
        bool c1 = (s == sidx2), c2 = (s == sidx2 + 1);
        if (c1 || c2) {
            // next iter's cru needs q only at its clique pixels
            #pragma unroll
            for (int c = 0; c < CC; ++c) q[p*CC + c] = acc[c];
        }
        float mx2 = acc[0];
        #pragma unroll
        for (int c = 1; c < CC; ++c) mx2 = fmaxf(mx2, acc[c]);
        float e[CC], ssum = 0.f;
        #pragma unroll
        for (int c = 0; c < CC; ++c) { e[c] = FEXP(acc[c] - mx2); ssum += e[c]; }
        float inv = FRCP(ssum);
        #pragma unroll
        for (int c = 0; c < CC; ++c) sm[c*HWN + p] = e[c] * inv;

        if (c1 || c2) {
            float* bkt = sums_next + (blockIdx.x & (NBKT-1)) * 64;
            float emx = FEXP(mx2);
            if (c1) {
                #pragma unroll
                for (int c = 0; c < CC; ++c) {
                    float ev = e[c] * emx;
                    atomicAdd(&bkt[c], ev - 1.0f);
                    float ea = (acc[c] == mx2) ? emx : ev * emx;
                    atomicAdd(&bkt[CC + c], ea - 1.0f);
                }
            } else {
                #pragma unroll
                for (int c = 0; c < CC; ++c) atomicAdd(&bkt[2*CC + c], e[c] * emx - 1.0f);
            }
        }
    } else {
        #pragma unroll
        for (int c = 0; c < CC; ++c) out[p*CC + c] = acc[c];
    }
}

// ---------------------------------------------------------------------------
extern "C" void kernel_launch(void* const* d_in, const int* in_sizes, int n_in,
                              void* d_out, int out_size, void* d_ws, size_t ws_size,
                              hipStream_t stream) {
    const float* un    = (const float*)d_in[0];
    const float* rgb   = (const float*)d_in[1];
    const int*   spin  = (const int*)  d_in[2];
    const int*   spidx = (const int*)  d_in[3];
    const float* skw   = (const float*)d_in[4];
    const float* bkw   = (const float*)d_in[5];
    const float* lw    = (const float*)d_in[6];
    const float* hwv   = (const float*)d_in[7];
    const float* cm    = (const float*)d_in[8];
    float* out = (float*)d_out;

    float* ws = (float*)d_ws;
    float* q     = ws;                     // pixel-major, sparse-valid
    float* sm    = ws + (size_t)CHW;       // channel-planar
    float* a     = ws + (size_t)2*CHW;     // combined pairwise (diag) / spatial
    float* b     = ws + (size_t)3*CHW;     // bilateral (dense fallback)
    float* guide = ws + (size_t)4*CHW;
    float* rsn   = guide + HWN;            // reciprocal norms
    float* rbn   = rsn + HWN;
    int*   spmT  = (int*)(rbn + HWN);
    float* M1t   = rbn + 2*(size_t)HWN;    // after spmT (HWN ints)
    float* M2t   = M1t + CC*CC;
    float* d1    = M2t + CC*CC;
    float* d2    = d1 + CC;
    int*   dflag = (int*)(d2 + CC);
    float* kbuf  = d2 + CC + 4;
    float* sums  = kbuf + 2*KS;            // NITER * NBKT * 64 floats

    dim3 blk(256);
    int gpix = HWN / 256;                  // 1024 blocks
    dim3 gblur(WW/TW, HH/TH, CC);          // 4 x 32 x 21
    dim3 gnorm(WW/TW, HH/TH, 1);

    k_init_small<<<1, 512, 0, stream>>>(cm, skw, bkw, M1t, M2t, d1, d2, dflag,
                                        kbuf, sums);
    k_init_maps<<<gpix, blk, 0, stream>>>(rgb, spin, un, guide, spmT, sm,
                                          spidx, sums);
    k_blur<<<gnorm, blk, 0, stream>>>(nullptr, guide, rsn, rbn,
                                      nullptr, nullptr, d1, d2, dflag, kbuf, 1);

    for (int it = 0; it < NITER; ++it) {
        int last = (it == NITER - 1) ? 1 : 0;
        float* su  = sums + it*NBKT*64;
        float* sun = last ? nullptr : (sums + (it+1)*NBKT*64);
        const float* qin = (it == 0) ? un : q;
        k_blur<<<gblur, blk, 0, stream>>>(sm, guide, a, b, rsn, rbn,
                                          d1, d2, dflag, kbuf, 0);
        k_update<<<gpix, blk, 0, stream>>>(un, qin, a, b, M1t, M2t, dflag,
                                           su, sun, lw, hwv,
                                           spmT, spidx, it, q, sm, out, last);
    }
}